// Round 1
// baseline (918.934 us; speedup 1.0000x reference)
//
#include <hip/hip_runtime.h>
#include <math.h>

#define HD    256
#define NHEAD 4
#define NSEG  1024

// ---------------------------------------------------------------------------
// K1: logits = tanh(x @ W1 + b1) @ W2 + b2   -> written to out_lg [N,4]
// 512 threads, 64 rows x 256 cols per block.
// thread: c = tid&63 -> cols 4c..4c+3 ; g = tid>>6 -> rows 8g..8g+7
// ---------------------------------------------------------------------------
#define K1_ROWS    64
#define K1_THREADS 512
#define K1_CHUNK   64

__device__ __forceinline__ float tanh_fast(float v) {
    float e = __expf(2.0f * v);                    // overflow->inf, tanh->1: ok
    return 1.0f - 2.0f * __builtin_amdgcn_rcpf(e + 1.0f);
}

__global__ __launch_bounds__(K1_THREADS) void k1_logits(
    const float* __restrict__ x, const float* __restrict__ W1,
    const float* __restrict__ b1, const float* __restrict__ W2,
    const float* __restrict__ b2, float* __restrict__ out_lg, int N)
{
    __shared__ float xs[K1_ROWS * HD];     // 64 KiB: x tile, row-major
    __shared__ float w1s[K1_CHUNK * HD];   // 64 KiB: W1 k-chunk

    const int tid = threadIdx.x;
    const int c = tid & 63;
    const int g = tid >> 6;
    const int rowbase = blockIdx.x * K1_ROWS;

    // stage x tile (coalesced float4)
    {
        const float4* xg = (const float4*)x;
        float4* xs4 = (float4*)xs;
        const size_t base = (size_t)rowbase * (HD / 4);
        const size_t last = (size_t)N * (HD / 4) - 1;
        #pragma unroll
        for (int it = 0; it < (K1_ROWS * HD / 4) / K1_THREADS; ++it) {
            size_t i = (size_t)it * K1_THREADS + tid;
            size_t gi = base + i; if (gi > last) gi = last;   // clamp (N%64==0 anyway)
            xs4[i] = xg[gi];
        }
    }

    float4 acc[8];
    {
        float4 bv = *(const float4*)(b1 + 4 * c);
        #pragma unroll
        for (int i = 0; i < 8; ++i) acc[i] = bv;
    }

    for (int kc = 0; kc < HD; kc += K1_CHUNK) {
        __syncthreads();   // previous chunk consumed (also covers xs staging)
        {
            const float4* wg = (const float4*)(W1 + (size_t)kc * HD);
            float4* ws4 = (float4*)w1s;
            #pragma unroll
            for (int it = 0; it < (K1_CHUNK * HD / 4) / K1_THREADS; ++it) {
                int i = it * K1_THREADS + tid;
                ws4[i] = wg[i];
            }
        }
        __syncthreads();
        #pragma unroll 4
        for (int k = 0; k < K1_CHUNK; ++k) {
            const float4 w = *(const float4*)&w1s[k * HD + 4 * c];
            const int kk = kc + k;
            #pragma unroll
            for (int i = 0; i < 8; ++i) {
                const float xv = xs[(8 * g + i) * HD + kk];   // wave-uniform broadcast
                acc[i].x = fmaf(xv, w.x, acc[i].x);
                acc[i].y = fmaf(xv, w.y, acc[i].y);
                acc[i].z = fmaf(xv, w.z, acc[i].z);
                acc[i].w = fmaf(xv, w.w, acc[i].w);
            }
        }
    }

    // epilogue: tanh, partial (K=4) second matmul, 64-lane butterfly reduce
    float w2a[4][NHEAD];
    #pragma unroll
    for (int e = 0; e < 4; ++e)
        #pragma unroll
        for (int h = 0; h < NHEAD; ++h)
            w2a[e][h] = W2[(size_t)(4 * c + e) * NHEAD + h];

    float p[8][NHEAD];
    #pragma unroll
    for (int i = 0; i < 8; ++i) {
        float t0 = tanh_fast(acc[i].x), t1 = tanh_fast(acc[i].y);
        float t2 = tanh_fast(acc[i].z), t3 = tanh_fast(acc[i].w);
        #pragma unroll
        for (int h = 0; h < NHEAD; ++h) {
            float v = t0 * w2a[0][h];
            v = fmaf(t1, w2a[1][h], v);
            v = fmaf(t2, w2a[2][h], v);
            v = fmaf(t3, w2a[3][h], v);
            p[i][h] = v;
        }
    }
    #pragma unroll
    for (int ofs = 32; ofs >= 1; ofs >>= 1)
        #pragma unroll
        for (int i = 0; i < 8; ++i)
            #pragma unroll
            for (int h = 0; h < NHEAD; ++h)
                p[i][h] += __shfl_xor(p[i][h], ofs, 64);

    if ((tid & 63) == 0) {
        float b2v[NHEAD];
        #pragma unroll
        for (int h = 0; h < NHEAD; ++h) b2v[h] = b2[h];
        #pragma unroll
        for (int i = 0; i < 8; ++i) {
            int row = rowbase + 8 * g + i;
            if (row < N) {
                #pragma unroll
                for (int h = 0; h < NHEAD; ++h)
                    out_lg[(size_t)row * NHEAD + h] = p[i][h] + b2v[h];
            }
        }
    }
}

// ---------------------------------------------------------------------------
// helpers
// ---------------------------------------------------------------------------
__device__ __forceinline__ int lower_bound(const int* __restrict__ a, int n, int v) {
    int lo = 0, hi = n;
    while (lo < hi) { int m = (lo + hi) >> 1; if (a[m] < v) lo = m + 1; else hi = m; }
    return lo;
}

// ---------------------------------------------------------------------------
// K2: per-segment max & sum-of-exp of logits; stats stashed at out[b*256+0..7]
// ---------------------------------------------------------------------------
__global__ __launch_bounds__(256) void k2_seg(
    const int* __restrict__ batch, const float* __restrict__ lg,
    float* __restrict__ out, int N)
{
    const int b = blockIdx.x;
    const int tid = threadIdx.x;
    const int lane = tid & 63, wid = tid >> 6;
    const int start = lower_bound(batch, N, b);
    const int end   = lower_bound(batch, N, b + 1);
    const float4* lg4 = (const float4*)lg;

    float4 mx = make_float4(-INFINITY, -INFINITY, -INFINITY, -INFINITY);
    for (int i = start + tid; i < end; i += 256) {
        float4 l = lg4[i];
        mx.x = fmaxf(mx.x, l.x); mx.y = fmaxf(mx.y, l.y);
        mx.z = fmaxf(mx.z, l.z); mx.w = fmaxf(mx.w, l.w);
    }
    #pragma unroll
    for (int ofs = 32; ofs >= 1; ofs >>= 1) {
        mx.x = fmaxf(mx.x, __shfl_xor(mx.x, ofs, 64));
        mx.y = fmaxf(mx.y, __shfl_xor(mx.y, ofs, 64));
        mx.z = fmaxf(mx.z, __shfl_xor(mx.z, ofs, 64));
        mx.w = fmaxf(mx.w, __shfl_xor(mx.w, ofs, 64));
    }
    __shared__ float4 red[4];
    if (lane == 0) red[wid] = mx;
    __syncthreads();
    float4 smax;
    smax.x = fmaxf(fmaxf(red[0].x, red[1].x), fmaxf(red[2].x, red[3].x));
    smax.y = fmaxf(fmaxf(red[0].y, red[1].y), fmaxf(red[2].y, red[3].y));
    smax.z = fmaxf(fmaxf(red[0].z, red[1].z), fmaxf(red[2].z, red[3].z));
    smax.w = fmaxf(fmaxf(red[0].w, red[1].w), fmaxf(red[2].w, red[3].w));
    __syncthreads();

    float4 sm = make_float4(0.f, 0.f, 0.f, 0.f);
    for (int i = start + tid; i < end; i += 256) {
        float4 l = lg4[i];
        sm.x += __expf(l.x - smax.x); sm.y += __expf(l.y - smax.y);
        sm.z += __expf(l.z - smax.z); sm.w += __expf(l.w - smax.w);
    }
    #pragma unroll
    for (int ofs = 32; ofs >= 1; ofs >>= 1) {
        sm.x += __shfl_xor(sm.x, ofs, 64);
        sm.y += __shfl_xor(sm.y, ofs, 64);
        sm.z += __shfl_xor(sm.z, ofs, 64);
        sm.w += __shfl_xor(sm.w, ofs, 64);
    }
    if (lane == 0) red[wid] = sm;
    __syncthreads();
    if (tid == 0) {
        float4 ssum;
        ssum.x = red[0].x + red[1].x + red[2].x + red[3].x;
        ssum.y = red[0].y + red[1].y + red[2].y + red[3].y;
        ssum.z = red[0].z + red[1].z + red[2].z + red[3].z;
        ssum.w = red[0].w + red[1].w + red[2].w + red[3].w;
        *(float4*)(out + (size_t)b * HD)     = smax;
        *(float4*)(out + (size_t)b * HD + 4) = ssum;
    }
}

// ---------------------------------------------------------------------------
// K3: attn = e/(sum+eps) (written in place over logits); z = sum attn*x;
//     graph_emb[b,:] = z @ Wt + (sum attn)*bt
// ---------------------------------------------------------------------------
__global__ __launch_bounds__(256) void k3_pool(
    const int* __restrict__ batch, const float* __restrict__ x,
    const float* __restrict__ Wt, const float* __restrict__ bt,
    float* __restrict__ out, int N)
{
    const int b = blockIdx.x;
    const int tid = threadIdx.x;
    const int start = lower_bound(batch, N, b);
    const int end   = lower_bound(batch, N, b + 1);

    float4* at4 = (float4*)(out + (size_t)NSEG * HD);   // logits now, attn after

    const float4 smax = *(const float4*)(out + (size_t)b * HD);
    const float4 ssum = *(const float4*)(out + (size_t)b * HD + 4);
    float4 inv;
    inv.x = 1.0f / (ssum.x + 1e-16f); inv.y = 1.0f / (ssum.y + 1e-16f);
    inv.z = 1.0f / (ssum.z + 1e-16f); inv.w = 1.0f / (ssum.w + 1e-16f);

    float z0 = 0.f, z1 = 0.f, z2 = 0.f, z3 = 0.f;
    __shared__ float4 attn_s[256];

    for (int c0 = start; c0 < end; c0 += 256) {
        const int idx = c0 + tid;
        if (idx < end) {
            float4 l = at4[idx];
            float4 a;
            a.x = __expf(l.x - smax.x) * inv.x;
            a.y = __expf(l.y - smax.y) * inv.y;
            a.z = __expf(l.z - smax.z) * inv.z;
            a.w = __expf(l.w - smax.w) * inv.w;
            at4[idx] = a;          // final attn output
            attn_s[tid] = a;
        }
        __syncthreads();
        const int cnt = min(256, end - c0);
        const float* xb = x + (size_t)c0 * HD + tid;
        #pragma unroll 4
        for (int i = 0; i < cnt; ++i) {
            float4 a = attn_s[i];
            float xv = xb[(size_t)i * HD];
            z0 = fmaf(a.x, xv, z0); z1 = fmaf(a.y, xv, z1);
            z2 = fmaf(a.z, xv, z2); z3 = fmaf(a.w, xv, z3);
        }
        __syncthreads();
    }

    __shared__ float zs[NHEAD][HD];
    zs[0][tid] = z0; zs[1][tid] = z1; zs[2][tid] = z2; zs[3][tid] = z3;
    __syncthreads();

    const int h = tid >> 6;                      // wave-uniform
    float smh, invh;
    if      (h == 0) { smh = ssum.x; invh = inv.x; }
    else if (h == 1) { smh = ssum.y; invh = inv.y; }
    else if (h == 2) { smh = ssum.z; invh = inv.z; }
    else             { smh = ssum.w; invh = inv.w; }

    float acc = smh * invh * bt[tid];            // (sum attn_h) * bt[j]
    #pragma unroll 4
    for (int k = 0; k < HD; ++k)
        acc = fmaf(zs[h][k], Wt[(size_t)k * HD + tid], acc);

    out[(size_t)b * HD + tid] = acc;             // overwrites stats stash: ok
}

// ---------------------------------------------------------------------------
extern "C" void kernel_launch(void* const* d_in, const int* in_sizes, int n_in,
                              void* d_out, int out_size, void* d_ws, size_t ws_size,
                              hipStream_t stream) {
    const float* x   = (const float*)d_in[0];
    const int*   bat = (const int*)  d_in[1];
    const float* W1  = (const float*)d_in[2];
    const float* b1  = (const float*)d_in[3];
    const float* W2  = (const float*)d_in[4];
    const float* b2  = (const float*)d_in[5];
    const float* Wt  = (const float*)d_in[6];
    const float* bt  = (const float*)d_in[7];
    float* out = (float*)d_out;
    const int N = in_sizes[0] / HD;

    float* out_lg = out + (size_t)NSEG * HD;   // attn region of d_out

    hipLaunchKernelGGL(k1_logits, dim3((N + K1_ROWS - 1) / K1_ROWS), dim3(K1_THREADS),
                       0, stream, x, W1, b1, W2, b2, out_lg, N);
    hipLaunchKernelGGL(k2_seg, dim3(NSEG), dim3(256), 0, stream, bat, out_lg, out, N);
    hipLaunchKernelGGL(k3_pool, dim3(NSEG), dim3(256), 0, stream, bat, x, Wt, bt, out, N);
}

// Round 3
// 434.815 us; speedup vs baseline: 2.1134x; 2.1134x over previous
//
#include <hip/hip_runtime.h>
#include <math.h>

#define HD    256
#define NHEAD 4
#define NSEG  1024

typedef short bf16x8 __attribute__((ext_vector_type(8)));
typedef float f32x16 __attribute__((ext_vector_type(16)));

__device__ __forceinline__ float tanh_fast(float v) {
    float e = __expf(2.0f * v);                    // overflow->inf, tanh->1: ok
    return 1.0f - 2.0f * __builtin_amdgcn_rcpf(e + 1.0f);
}

// split fp32 pair into packed bf16-hi word and bf16-lo word (truncation split;
// lo captures mantissa bits 9..17 -> per-product rel err ~2^-17)
__device__ __forceinline__ void split2(float a, float b, unsigned &hi, unsigned &lo) {
    unsigned ba = __float_as_uint(a), bb = __float_as_uint(b);
    unsigned ha = ba & 0xFFFF0000u, hb = bb & 0xFFFF0000u;
    float la = a - __uint_as_float(ha);
    float lb = b - __uint_as_float(hb);
    hi = (ha >> 16) | hb;
    lo = (__float_as_uint(la) >> 16) | (__float_as_uint(lb) & 0xFFFF0000u);
}

// ---------------------------------------------------------------------------
// K1: logits = tanh(x @ W1 + b1) @ W2 + b2  via split-bf16 MFMA.
// 512 thr = 8 waves: rg = wid>>1 (4 row groups x 64 rows), cg = wid&1 (2 col
// groups x 128 cols). Wave: 64 rows x 128 cols = 2 rowtiles x 4 coltiles of
// 32x32 mfma. K-chunks of 64 staged in LDS as bf16 hi/lo planes, [col][k]
// layout, XOR-swizzled (kbyte ^ (col&7)<<4) for bank-balanced ds_read_b128.
// VGPR note: acc alone = 128 VGPR -> do NOT set min-waves in launch_bounds
// (a 128-VGPR cap would force accumulator spills). 1 block/CU, 2 waves/SIMD.
// ---------------------------------------------------------------------------
#define K1_THREADS 512
#define BM 256
#define K1_LDS (65536 + 4096)

__global__ __launch_bounds__(K1_THREADS) void k1_mfma(
    const float* __restrict__ x, const float* __restrict__ W1,
    const float* __restrict__ b1, const float* __restrict__ W2,
    const float* __restrict__ b2, float* __restrict__ out_lg, int N)
{
    extern __shared__ __align__(16) char smem[];   // [0,32K) w_hi, [32K,64K) w_lo, [64K,+4K) p_lds
    float (*p_lds)[4] = (float(*)[4])(smem + 65536);

    const int tid  = threadIdx.x;
    const int lane = tid & 63;
    const int lo5  = lane & 31;
    const int hi   = lane >> 5;
    const int wid  = tid >> 6;
    const int rg   = wid >> 1;
    const int cg   = wid & 1;
    const int c0   = cg * 128;
    const int blkrow = blockIdx.x * BM;

    f32x16 acc[2][4];
    #pragma unroll
    for (int ct = 0; ct < 4; ++ct) {
        float b1v = b1[c0 + ct*32 + lo5];
        #pragma unroll
        for (int rt = 0; rt < 2; ++rt)
            #pragma unroll
            for (int e = 0; e < 16; ++e)
                acc[rt][ct][e] = b1v;
    }

    int rA[2];
    #pragma unroll
    for (int rt = 0; rt < 2; ++rt) {
        int r = blkrow + rg*64 + rt*32 + lo5;
        rA[rt] = r < N ? r : N - 1;                // tail clamp; writes guarded
    }

    const int colS  = tid & 255;                   // staging: thread -> (col, k-half)
    const int khalf = tid >> 8;
    const unsigned swzS = (colS & 7) << 4;

    for (int kc = 0; kc < HD; kc += 64) {
        __syncthreads();                           // LDS reuse guard
        {   // stage W1 k-chunk -> bf16 hi/lo planes, transposed [col][k], swizzled
            const float* wb = W1 + (size_t)(kc + khalf*32) * HD + colS;
            #pragma unroll
            for (int i = 0; i < 16; ++i) {
                float w0 = wb[(2*i) * HD];
                float w1 = wb[(2*i+1) * HD];
                unsigned hw, lw;
                split2(w0, w1, hw, lw);
                int off = colS*128 + ((((khalf*32 + 2*i))*2) ^ swzS);
                *(unsigned*)(smem + off)         = hw;
                *(unsigned*)(smem + 32768 + off) = lw;
            }
        }
        __syncthreads();

        #pragma unroll
        for (int ks = 0; ks < 4; ++ks) {
            union { unsigned u[4]; bf16x8 v; } ah[2], al[2];
            #pragma unroll
            for (int rt = 0; rt < 2; ++rt) {       // A: x direct from global, split in-reg
                const float* xp = x + (size_t)rA[rt]*HD + kc + ks*16 + hi*8;
                float4 q0 = *(const float4*)xp;
                float4 q1 = *(const float4*)(xp + 4);
                split2(q0.x, q0.y, ah[rt].u[0], al[rt].u[0]);
                split2(q0.z, q0.w, ah[rt].u[1], al[rt].u[1]);
                split2(q1.x, q1.y, ah[rt].u[2], al[rt].u[2]);
                split2(q1.z, q1.w, ah[rt].u[3], al[rt].u[3]);
            }
            #pragma unroll
            for (int ct = 0; ct < 4; ++ct) {
                int colB = c0 + ct*32 + lo5;
                int off  = colB*128 + ((((ks*16 + hi*8))*2) ^ ((colB & 7) << 4));
                bf16x8 bh = *(const bf16x8*)(smem + off);
                bf16x8 bl = *(const bf16x8*)(smem + 32768 + off);
                #pragma unroll
                for (int rt = 0; rt < 2; ++rt) {
                    acc[rt][ct] = __builtin_amdgcn_mfma_f32_32x32x16_bf16(ah[rt].v, bh, acc[rt][ct], 0, 0, 0);
                    acc[rt][ct] = __builtin_amdgcn_mfma_f32_32x32x16_bf16(ah[rt].v, bl, acc[rt][ct], 0, 0, 0);
                    acc[rt][ct] = __builtin_amdgcn_mfma_f32_32x32x16_bf16(al[rt].v, bh, acc[rt][ct], 0, 0, 0);
                }
            }
        }
    }

    // epilogue: tanh -> h@W2 partial per lane -> butterfly over 32-lane half
    #pragma unroll
    for (int rt = 0; rt < 2; ++rt)
        #pragma unroll
        for (int ct = 0; ct < 4; ++ct)
            #pragma unroll
            for (int e = 0; e < 16; ++e)
                acc[rt][ct][e] = tanh_fast(acc[rt][ct][e]);

    float4 w2v[4];
    #pragma unroll
    for (int ct = 0; ct < 4; ++ct)
        w2v[ct] = *(const float4*)(W2 + (size_t)(c0 + ct*32 + lo5) * NHEAD);

    float4 mine = make_float4(0.f, 0.f, 0.f, 0.f);
    #pragma unroll
    for (int rt = 0; rt < 2; ++rt) {
        #pragma unroll
        for (int e = 0; e < 16; ++e) {
            float s0 = 0.f, s1 = 0.f, s2 = 0.f, s3 = 0.f;
            #pragma unroll
            for (int ct = 0; ct < 4; ++ct) {
                float t = acc[rt][ct][e];
                s0 = fmaf(t, w2v[ct].x, s0);
                s1 = fmaf(t, w2v[ct].y, s1);
                s2 = fmaf(t, w2v[ct].z, s2);
                s3 = fmaf(t, w2v[ct].w, s3);
            }
            #pragma unroll
            for (int o = 16; o >= 1; o >>= 1) {    // offsets <32: halves stay separate
                s0 += __shfl_xor(s0, o, 64);
                s1 += __shfl_xor(s1, o, 64);
                s2 += __shfl_xor(s2, o, 64);
                s3 += __shfl_xor(s3, o, 64);
            }
            if (lo5 == rt*16 + e) mine = make_float4(s0, s1, s2, s3);
        }
    }
    const int e_m = lo5 & 15, rt_m = lo5 >> 4;
    const int myrow = rg*64 + rt_m*32 + (e_m & 3) + 8*(e_m >> 2) + 4*hi;

    if (cg == 0) {
        p_lds[myrow][0] = mine.x; p_lds[myrow][1] = mine.y;
        p_lds[myrow][2] = mine.z; p_lds[myrow][3] = mine.w;
    }
    __syncthreads();
    if (cg == 1) {
        p_lds[myrow][0] += mine.x; p_lds[myrow][1] += mine.y;
        p_lds[myrow][2] += mine.z; p_lds[myrow][3] += mine.w;
    }
    __syncthreads();
    if (tid < BM) {
        int grow = blkrow + tid;
        if (grow < N) {
            float4 r = *(float4*)p_lds[tid];
            float4 o;
            o.x = r.x + b2[0]; o.y = r.y + b2[1];
            o.z = r.z + b2[2]; o.w = r.w + b2[3];
            *(float4*)(out_lg + (size_t)grow * NHEAD) = o;
        }
    }
}

// ---------------------------------------------------------------------------
__device__ __forceinline__ int lower_bound(const int* __restrict__ a, int n, int v) {
    int lo = 0, hi = n;
    while (lo < hi) { int m = (lo + hi) >> 1; if (a[m] < v) lo = m + 1; else hi = m; }
    return lo;
}

// ---------------------------------------------------------------------------
// K2: per-segment max & sum-of-exp of logits; stats stashed at out[b*256+0..7]
// ---------------------------------------------------------------------------
__global__ __launch_bounds__(256) void k2_seg(
    const int* __restrict__ batch, const float* __restrict__ lg,
    float* __restrict__ out, int N)
{
    const int b = blockIdx.x;
    const int tid = threadIdx.x;
    const int lane = tid & 63, wid = tid >> 6;
    const int start = lower_bound(batch, N, b);
    const int end   = lower_bound(batch, N, b + 1);
    const float4* lg4 = (const float4*)lg;

    float4 mx = make_float4(-INFINITY, -INFINITY, -INFINITY, -INFINITY);
    for (int i = start + tid; i < end; i += 256) {
        float4 l = lg4[i];
        mx.x = fmaxf(mx.x, l.x); mx.y = fmaxf(mx.y, l.y);
        mx.z = fmaxf(mx.z, l.z); mx.w = fmaxf(mx.w, l.w);
    }
    #pragma unroll
    for (int ofs = 32; ofs >= 1; ofs >>= 1) {
        mx.x = fmaxf(mx.x, __shfl_xor(mx.x, ofs, 64));
        mx.y = fmaxf(mx.y, __shfl_xor(mx.y, ofs, 64));
        mx.z = fmaxf(mx.z, __shfl_xor(mx.z, ofs, 64));
        mx.w = fmaxf(mx.w, __shfl_xor(mx.w, ofs, 64));
    }
    __shared__ float4 red[4];
    if (lane == 0) red[wid] = mx;
    __syncthreads();
    float4 smax;
    smax.x = fmaxf(fmaxf(red[0].x, red[1].x), fmaxf(red[2].x, red[3].x));
    smax.y = fmaxf(fmaxf(red[0].y, red[1].y), fmaxf(red[2].y, red[3].y));
    smax.z = fmaxf(fmaxf(red[0].z, red[1].z), fmaxf(red[2].z, red[3].z));
    smax.w = fmaxf(fmaxf(red[0].w, red[1].w), fmaxf(red[2].w, red[3].w));
    __syncthreads();

    float4 sm = make_float4(0.f, 0.f, 0.f, 0.f);
    for (int i = start + tid; i < end; i += 256) {
        float4 l = lg4[i];
        sm.x += __expf(l.x - smax.x); sm.y += __expf(l.y - smax.y);
        sm.z += __expf(l.z - smax.z); sm.w += __expf(l.w - smax.w);
    }
    #pragma unroll
    for (int ofs = 32; ofs >= 1; ofs >>= 1) {
        sm.x += __shfl_xor(sm.x, ofs, 64);
        sm.y += __shfl_xor(sm.y, ofs, 64);
        sm.z += __shfl_xor(sm.z, ofs, 64);
        sm.w += __shfl_xor(sm.w, ofs, 64);
    }
    if (lane == 0) red[wid] = sm;
    __syncthreads();
    if (tid == 0) {
        float4 ssum;
        ssum.x = red[0].x + red[1].x + red[2].x + red[3].x;
        ssum.y = red[0].y + red[1].y + red[2].y + red[3].y;
        ssum.z = red[0].z + red[1].z + red[2].z + red[3].z;
        ssum.w = red[0].w + red[1].w + red[2].w + red[3].w;
        *(float4*)(out + (size_t)b * HD)     = smax;
        *(float4*)(out + (size_t)b * HD + 4) = ssum;
    }
}

// ---------------------------------------------------------------------------
// K3: attn = e/(sum+eps) (in place over logits); z = sum attn*x;
//     graph_emb[b,:] = z @ Wt + (sum attn)*bt
// ---------------------------------------------------------------------------
__global__ __launch_bounds__(256) void k3_pool(
    const int* __restrict__ batch, const float* __restrict__ x,
    const float* __restrict__ Wt, const float* __restrict__ bt,
    float* __restrict__ out, int N)
{
    const int b = blockIdx.x;
    const int tid = threadIdx.x;
    const int start = lower_bound(batch, N, b);
    const int end   = lower_bound(batch, N, b + 1);

    float4* at4 = (float4*)(out + (size_t)NSEG * HD);   // logits now, attn after

    const float4 smax = *(const float4*)(out + (size_t)b * HD);
    const float4 ssum = *(const float4*)(out + (size_t)b * HD + 4);
    float4 inv;
    inv.x = 1.0f / (ssum.x + 1e-16f); inv.y = 1.0f / (ssum.y + 1e-16f);
    inv.z = 1.0f / (ssum.z + 1e-16f); inv.w = 1.0f / (ssum.w + 1e-16f);

    float z0 = 0.f, z1 = 0.f, z2 = 0.f, z3 = 0.f;
    __shared__ float4 attn_s[256];

    for (int c0 = start; c0 < end; c0 += 256) {
        const int idx = c0 + tid;
        if (idx < end) {
            float4 l = at4[idx];
            float4 a;
            a.x = __expf(l.x - smax.x) * inv.x;
            a.y = __expf(l.y - smax.y) * inv.y;
            a.z = __expf(l.z - smax.z) * inv.z;
            a.w = __expf(l.w - smax.w) * inv.w;
            at4[idx] = a;          // final attn output
            attn_s[tid] = a;
        }
        __syncthreads();
        const int cnt = min(256, end - c0);
        const float* xb = x + (size_t)c0 * HD + tid;
        #pragma unroll 4
        for (int i = 0; i < cnt; ++i) {
            float4 a = attn_s[i];
            float xv = xb[(size_t)i * HD];
            z0 = fmaf(a.x, xv, z0); z1 = fmaf(a.y, xv, z1);
            z2 = fmaf(a.z, xv, z2); z3 = fmaf(a.w, xv, z3);
        }
        __syncthreads();
    }

    __shared__ float zs[NHEAD][HD];
    zs[0][tid] = z0; zs[1][tid] = z1; zs[2][tid] = z2; zs[3][tid] = z3;
    __syncthreads();

    const int h = tid >> 6;                      // wave-uniform
    float smh, invh;
    if      (h == 0) { smh = ssum.x; invh = inv.x; }
    else if (h == 1) { smh = ssum.y; invh = inv.y; }
    else if (h == 2) { smh = ssum.z; invh = inv.z; }
    else             { smh = ssum.w; invh = inv.w; }

    float acc = smh * invh * bt[tid];            // (sum attn_h) * bt[j]
    #pragma unroll 4
    for (int k = 0; k < HD; ++k)
        acc = fmaf(zs[h][k], Wt[(size_t)k * HD + tid], acc);

    out[(size_t)b * HD + tid] = acc;             // overwrites stats stash: ok
}

// ---------------------------------------------------------------------------
extern "C" void kernel_launch(void* const* d_in, const int* in_sizes, int n_in,
                              void* d_out, int out_size, void* d_ws, size_t ws_size,
                              hipStream_t stream) {
    const float* x   = (const float*)d_in[0];
    const int*   bat = (const int*)  d_in[1];
    const float* W1  = (const float*)d_in[2];
    const float* b1  = (const float*)d_in[3];
    const float* W2  = (const float*)d_in[4];
    const float* b2  = (const float*)d_in[5];
    const float* Wt  = (const float*)d_in[6];
    const float* bt  = (const float*)d_in[7];
    float* out = (float*)d_out;
    const int N = in_sizes[0] / HD;

    float* out_lg = out + (size_t)NSEG * HD;   // attn region of d_out

    hipLaunchKernelGGL(k1_mfma, dim3((N + BM - 1) / BM), dim3(K1_THREADS),
                       K1_LDS, stream, x, W1, b1, W2, b2, out_lg, N);
    hipLaunchKernelGGL(k2_seg, dim3(NSEG), dim3(256), 0, stream, bat, out_lg, out, N);
    hipLaunchKernelGGL(k3_pool, dim3(NSEG), dim3(256), 0, stream, bat, x, Wt, bt, out, N);
}